// Round 8
// baseline (275.384 us; speedup 1.0000x reference)
//
#include <hip/hip_runtime.h>
#include <hip/hip_bf16.h>
#include <cstdint>

typedef __attribute__((ext_vector_type(8))) __bf16 bf16v8;
typedef __attribute__((ext_vector_type(4))) float f32x4;
typedef __attribute__((ext_vector_type(4))) unsigned short ushort4v;
typedef __attribute__((ext_vector_type(8))) unsigned short ushort8v;

#define BB 8
#define NN 2048
#define DD 768

__device__ __forceinline__ float b2f(unsigned short u) {
  union { unsigned int i; float f; } c; c.i = ((unsigned int)u) << 16; return c.f;
}
__device__ __forceinline__ unsigned short f2b(float f) {
  union { float f; unsigned int i; } c; c.f = f;
  unsigned int u = c.i;
  return (unsigned short)((u + 0x7fffu + ((u >> 16) & 1u)) >> 16);
}

// ---------------- LayerNorm: f32 [16384][768] -> bf16 ----------------
__global__ __launch_bounds__(256) void ln_kernel(const float* __restrict__ x,
                                                 const float* __restrict__ gamma,
                                                 const float* __restrict__ beta,
                                                 unsigned short* __restrict__ xb) {
  int row = blockIdx.x;
  const float* xr = x + (size_t)row * DD;
  int t = threadIdx.x;
  float a0 = xr[t], a1 = xr[t + 256], a2 = xr[t + 512];
  float s = a0 + a1 + a2;
  float q = a0 * a0 + a1 * a1 + a2 * a2;
  for (int o = 32; o > 0; o >>= 1) { s += __shfl_xor(s, o); q += __shfl_xor(q, o); }
  __shared__ float red[2][4];
  int w = t >> 6, lane = t & 63;
  if (lane == 0) { red[0][w] = s; red[1][w] = q; }
  __syncthreads();
  s = red[0][0] + red[0][1] + red[0][2] + red[0][3];
  q = red[1][0] + red[1][1] + red[1][2] + red[1][3];
  float mean = s * (1.0f / DD);
  float var = q * (1.0f / DD) - mean * mean;
  float inv = rsqrtf(var + 1e-5f);
  unsigned short* o0 = xb + (size_t)row * DD;
  o0[t]       = f2b((a0 - mean) * inv * gamma[t]       + beta[t]);
  o0[t + 256] = f2b((a1 - mean) * inv * gamma[t + 256] + beta[t + 256]);
  o0[t + 512] = f2b((a2 - mean) * inv * gamma[t + 512] + beta[t + 512]);
}

// ------------- Weight concat/convert: Wcat[2304][768] bf16, scale folded into Wq -------------
__global__ __launch_bounds__(256) void wconvert(const float* __restrict__ Wq,
                                                const float* __restrict__ Wk,
                                                const float* __restrict__ Wv,
                                                unsigned short* __restrict__ Wcat) {
  int i = blockIdx.x * 256 + threadIdx.x;
  const int dd = DD * DD;
  if (i >= 3 * dd) return;
  float v;
  if (i < dd)           v = Wq[i] * 0.03608439182435161f;   // 1/sqrt(768)
  else if (i < 2 * dd)  v = Wk[i - dd];
  else                  v = Wv[i - 2 * dd];
  Wcat[i] = f2b(v);
}

// ---------------- async global->LDS (16B per lane, wave-uniform LDS base) ----------------
__device__ __forceinline__ void gload_lds16(const void* g, void* l) {
  __builtin_amdgcn_global_load_lds(
      (const __attribute__((address_space(1))) void*)g,
      (__attribute__((address_space(3))) void*)(unsigned)(uintptr_t)l,
      16, 0, 0);
}

// LDS geometry (elements): buffer b at b*32768.
//   slot A-ks at  buf + ks*8192          (256 rows x 32 cols, 64B rows)
//   slot B-ks at  buf + 16384 + ks*8192  (B slot sized for 256 rows; only BN rows read)
#define RDA(i0, ks, B)                                                                   \
  _Pragma("unroll")                                                                      \
  for (int i_ = 0; i_ < 4; ++i_)                                                         \
    aq[i_] = *(const bf16v8*)&smem[(B) + (ks) * 8192 + arow0 + ((i0) + i_) * 512 + kg8];
#define RDB(ks, B)                                                                       \
  _Pragma("unroll")                                                                      \
  for (int j_ = 0; j_ < NJ; ++j_)                                                        \
    bq[j_] = *(const bf16v8*)&smem[(B) + 16384 + (ks) * 8192 + brow0 + j_ * 512 + kg8];
#define MFQ(i0)                                                                          \
  _Pragma("unroll")                                                                      \
  for (int i_ = 0; i_ < 4; ++i_) {                                                       \
    _Pragma("unroll")                                                                    \
    for (int j_ = 0; j_ < NJ; ++j_)                                                      \
      acc[(i0) + i_][j_] = __builtin_amdgcn_mfma_f32_16x16x32_bf16(                      \
          aq[i_], bq[j_], acc[(i0) + i_][j_], 0, 0, 0);                                  \
  }
#define BARF asm volatile("s_barrier" ::: "memory")
#define VMC6 asm volatile("s_waitcnt vmcnt(6)" ::: "memory")
#define VMC0 asm volatile("s_waitcnt vmcnt(0)" ::: "memory")
#define P1   __builtin_amdgcn_s_setprio(1)
#define P0   __builtin_amdgcn_s_setprio(0)

// One K-tile = 4 balanced phases over a LINEAR K-tile stream q (tile = q/NTT, k = q%NTT).
// Stage ledger (unchanged from r6, now crossing output-tile boundaries):
//   ph1: stage ks1(q+1) -> NXTB    ph2: stage ks1(q+1) B -> NXTB
//   ph3: stage ks0(q+2) -> CURB    ph4: stage ks0(q+2) B -> CURB
//   VMC6 at ph2/ph4 ends; VMC0 only at q == NTtot-2. Mid-stream C-stores are vmcnt-newer
//   than all pending staged loads, so FIFO drains remain safe.
#define TILEK(KT, CURB, NXTB)                                                            \
  do {                                                                                   \
    /* ---- phase 1: quad rows 0-3, ks0 */                                               \
    RDA(0, 0, CURB); RDB(0, CURB);                                                       \
    if ((KT) + 1 < NTtot) stgA((KT) + 1, 1, (NXTB));                                     \
    BARF; P1; MFQ(0); P0; BARF;                                                          \
    /* ---- phase 2: quad rows 4-7, ks0 (bq reused) */                                   \
    RDA(4, 0, CURB);                                                                     \
    if ((KT) + 1 < NTtot) stgB((KT) + 1, 1, (NXTB));                                     \
    BARF; P1; MFQ(4); P0;                                                                \
    VMC6; BARF;                                                                          \
    /* ---- phase 3: quad rows 0-3, ks1 */                                               \
    RDA(0, 1, CURB); RDB(1, CURB);                                                       \
    if ((KT) + 2 < NTtot) stgA((KT) + 2, 0, (CURB));                                     \
    BARF; P1; MFQ(0); P0; BARF;                                                          \
    /* ---- phase 4: quad rows 4-7, ks1 */                                               \
    RDA(4, 1, CURB);                                                                     \
    if ((KT) + 2 < NTtot) stgB((KT) + 2, 0, (CURB));                                     \
    BARF; P1; MFQ(4); P0;                                                                \
    if ((KT) < NTtot - 2) { VMC6; } else { VMC0; }                                       \
    BARF;                                                                                \
  } while (0)

// ---- Persistent multi-tile 256xBN GEMM, C = A*B^T. 256 blocks (1/CU). Each block runs
// TPB output tiles (shared m0, n-step NSTEP) as one continuous pipelined K-stream.
// MODE 0: QKV epilogue   MODE 1: bf16 store   MODE 2: f32 store
template <int MODE, int NJ, int NTT, int TPB, int NSTEP, int IDXB>
__global__ __launch_bounds__(512, 2) void gemmP(
    const unsigned short* __restrict__ A, const unsigned short* __restrict__ Bm,
    unsigned short* __restrict__ Cq, unsigned short* __restrict__ Ck,
    unsigned short* __restrict__ Cv, float* __restrict__ Cf,
    int lda, int ldb,
    long aStride, long bStride, long cStride) {
  extern __shared__ unsigned short smem[];      // 65536 elems = 131072 B
  constexpr int BN = NJ * 64;
  constexpr int NTtot = NTT * TPB;

  const int t = threadIdx.x;
  // physical->logical: each XCD (bid&7) owns a contiguous chunk of 32 logical blocks
  const int lid = (blockIdx.x & 7) * 32 + (blockIdx.x >> 3);
  const int bz = lid / IDXB;
  const int idx = lid % IDXB;
  const int m0 = (idx >> 2) * 256;
  const int n0b = (idx & 3) * BN;
  const unsigned short* Ab = A + (size_t)bz * aStride;
  const unsigned short* Bb = Bm + (size_t)bz * bStride;

  const int lane = t & 63;
  const int w = t >> 6;
  const int wm = w >> 2, wn = w & 3;            // 2 x 4 wave grid
  const int frow = lane & 15;
  const int kg8 = (lane >> 4) * 8;
  const int arow0 = (wm * 128 + frow) * 32;
  const int brow0 = (wn * (NJ * 16) + frow) * 32;

  // staging: thread t covers slot row (t>>2), k-group (t&3); +128-row half via +4096 elems
  const int srow = t >> 2;
  const int scol8 = (t & 3) * 8;
  const unsigned short* AsrcB = Ab + (size_t)(m0 + srow) * lda + scol8;
  const unsigned short* BsrcB = Bb + (size_t)(n0b + srow) * ldb + scol8;
  const size_t bTileStep = (size_t)NSTEP * ldb;
  const int sdst = w * 512;

  auto stgA = [&](int kq, int ks, int bufb) {
    const int kk = kq % NTT;
    const unsigned short* s = AsrcB + kk * 64 + ks * 32;
    gload_lds16(s, &smem[bufb + ks * 8192 + sdst]);
    gload_lds16(s + (size_t)128 * lda, &smem[bufb + ks * 8192 + 4096 + sdst]);
  };
  auto stgB = [&](int kq, int ks, int bufb) {
    const int tt = kq / NTT, kk = kq % NTT;
    const unsigned short* s = BsrcB + (size_t)tt * bTileStep + kk * 64 + ks * 32;
    gload_lds16(s, &smem[bufb + 16384 + ks * 8192 + sdst]);
    gload_lds16(s + (size_t)128 * ldb, &smem[bufb + 16384 + ks * 8192 + 4096 + sdst]);
  };

  f32x4 acc[8][NJ] = {};
  bf16v8 aq[4], bq[NJ];

  // Epilogue writer for tile tt. C/D layout: col=lane&15, row=(lane>>4)*4+reg [HW-verified]
  const int r0 = (lane >> 4) * 4;
  const int c0 = lane & 15;
  const int mrowB = m0 + wm * 128 + r0;
  auto writeC = [&](int tt) {
    const int n0w = n0b + tt * NSTEP;
    const int ncolB = n0w + wn * (NJ * 16) + c0;
    if (MODE == 0) {
      if (n0w < 1536) {  // Q or K region (block-uniform: BN | 768)
        unsigned short* dst = (n0w < 768) ? Cq : Ck;
        const int cb = (n0w < 768) ? 0 : 768;
#pragma unroll
        for (int i = 0; i < 8; ++i)
#pragma unroll
          for (int j = 0; j < NJ; ++j)
#pragma unroll
            for (int r = 0; r < 4; ++r)
              dst[(size_t)(mrowB + i * 16 + r) * DD + (ncolB + j * 16 - cb)] = f2b(acc[i][j][r]);
      } else {  // V region: store transposed Vt[b][e][n]
#pragma unroll
        for (int i = 0; i < 8; ++i) {
          int row = mrowB + i * 16;
          int bb = row >> 11, nn = row & 2047;
#pragma unroll
          for (int j = 0; j < NJ; ++j) {
            int e = ncolB + j * 16 - 1536;
            ushort4v pk;
#pragma unroll
            for (int r = 0; r < 4; ++r) pk[r] = f2b(acc[i][j][r]);
            *(ushort4v*)&Cv[((size_t)(bb * DD + e)) * NN + nn] = pk;
          }
        }
      }
    } else if (MODE == 1) {
      unsigned short* dst = Cq + (size_t)bz * cStride;
#pragma unroll
      for (int i = 0; i < 8; ++i)
#pragma unroll
        for (int j = 0; j < NJ; ++j)
#pragma unroll
          for (int r = 0; r < 4; ++r)
            dst[(size_t)(mrowB + i * 16 + r) * NN + (ncolB + j * 16)] = f2b(acc[i][j][r]);
    } else {
      float* dst = Cf + (size_t)bz * cStride;
#pragma unroll
      for (int i = 0; i < 8; ++i)
#pragma unroll
        for (int j = 0; j < NJ; ++j)
#pragma unroll
          for (int r = 0; r < 4; ++r)
            dst[(size_t)(mrowB + i * 16 + r) * DD + (ncolB + j * 16)] = acc[i][j][r];
    }
  };

  // prologue: q0 both ks + q1 ks0; vmcnt(8) retires q0-ks0 (oldest 4 loads)
  stgA(0, 0, 0);     stgB(0, 0, 0);
  stgA(0, 1, 0);     stgB(0, 1, 0);
  stgA(1, 0, 32768); stgB(1, 0, 32768);
  asm volatile("s_waitcnt vmcnt(8)" ::: "memory");
  BARF;

  for (int q = 0; q < NTtot; q += 2) {
    TILEK(q, 0, 32768);
    TILEK(q + 1, 32768, 0);
    if (((q + 2) % NTT) == 0) {           // output-tile boundary (NTT even)
      writeC((q + 2) / NTT - 1);
#pragma unroll
      for (int i = 0; i < 8; ++i)
#pragma unroll
        for (int j = 0; j < NJ; ++j) acc[i][j] = f32x4{0.f, 0.f, 0.f, 0.f};
    }
  }
}

// ---------------- masked softmax, in-place on bf16 S rows ----------------
__global__ __launch_bounds__(256) void softmax_mask(unsigned short* __restrict__ S,
                                                    const int* __restrict__ mask) {
  int row = blockIdx.x;            // 0..16383
  int bb = row >> 11;
  unsigned short* sr = S + (size_t)row * NN;
  const int* mr = mask + bb * NN;
  int t = threadIdx.x;

  ushort8v pk = *(const ushort8v*)&sr[t * 8];
  float v[8];
  int msk[8];
#pragma unroll
  for (int j = 0; j < 8; ++j) msk[j] = mr[t * 8 + j];
  float mx = -1e30f;
#pragma unroll
  for (int j = 0; j < 8; ++j) {
    v[j] = b2f(pk[j]);
    if (!msk[j]) mx = fmaxf(mx, v[j]);
  }
  for (int o = 32; o > 0; o >>= 1) mx = fmaxf(mx, __shfl_xor(mx, o));
  __shared__ float redm[4], reds[4];
  int w = t >> 6, lane = t & 63;
  if (lane == 0) redm[w] = mx;
  __syncthreads();
  mx = fmaxf(fmaxf(redm[0], redm[1]), fmaxf(redm[2], redm[3]));

  float e[8];
  float sum = 0.f;
#pragma unroll
  for (int j = 0; j < 8; ++j) {
    e[j] = msk[j] ? 0.f : __expf(v[j] - mx);
    sum += e[j];
  }
  for (int o = 32; o > 0; o >>= 1) sum += __shfl_xor(sum, o);
  if (lane == 0) reds[w] = sum;
  __syncthreads();
  sum = reds[0] + reds[1] + reds[2] + reds[3];
  float inv = 1.0f / sum;

  ushort8v op;
#pragma unroll
  for (int j = 0; j < 8; ++j) op[j] = f2b(e[j] * inv);
  *(ushort8v*)&sr[t * 8] = op;
}

extern "C" void kernel_launch(void* const* d_in, const int* in_sizes, int n_in,
                              void* d_out, int out_size, void* d_ws, size_t ws_size,
                              hipStream_t stream) {
  const float* features = (const float*)d_in[0];
  const int* mask       = (const int*)d_in[1];
  const float* Wq       = (const float*)d_in[2];
  const float* Wk       = (const float*)d_in[3];
  const float* Wv       = (const float*)d_in[4];
  const float* gamma    = (const float*)d_in[5];
  const float* beta     = (const float*)d_in[6];
  float* out = (float*)d_out;

  char* ws = (char*)d_ws;
  size_t off = 0;
  auto alloc = [&](size_t bytes) {
    char* p = ws + off;
    off += (bytes + 255) & ~(size_t)255;
    return p;
  };
  // Wcat padded by 64 rows (192-wide B staging over-read at the last N-tile)
  unsigned short* Wcat = (unsigned short*)alloc((size_t)(2304 + 64) * DD * 2);
  unsigned short* Qb   = (unsigned short*)alloc((size_t)BB * NN * DD * 2);
  unsigned short* Kb   = (unsigned short*)alloc((size_t)BB * NN * DD * 2);
  // Vt padded by 64 rows of 2048 (over-read at last e-tile of last batch)
  unsigned short* Vt   = (unsigned short*)alloc(((size_t)BB * DD + 64) * NN * 2);
  // S (67 MB) aliases the X buffer region: X is dead once GEMM0 completes.
  char* last = alloc((size_t)BB * NN * NN * 2);
  unsigned short* Sb = (unsigned short*)last;
  unsigned short* Xb = (unsigned short*)last;  // first 25 MB of the S region

  // allow 128 KiB dynamic LDS (idempotent host-side config; not a stream op)
  (void)hipFuncSetAttribute(reinterpret_cast<const void*>(&gemmP<0, 3, 12, 3, 768, 256>),
                            hipFuncAttributeMaxDynamicSharedMemorySize, 131072);
  (void)hipFuncSetAttribute(reinterpret_cast<const void*>(&gemmP<1, 4, 12, 2, 1024, 32>),
                            hipFuncAttributeMaxDynamicSharedMemorySize, 131072);
  (void)hipFuncSetAttribute(reinterpret_cast<const void*>(&gemmP<2, 3, 32, 1, 0, 32>),
                            hipFuncAttributeMaxDynamicSharedMemorySize, 131072);

  ln_kernel<<<BB * NN, 256, 0, stream>>>(features, gamma, beta, Xb);
  wconvert<<<(3 * DD * DD + 255) / 256, 256, 0, stream>>>(Wq, Wk, Wv, Wcat);

  // QKV projection: [16384,768] x [2304,768]^T ; 256 blocks x 3 tiles (36 K-tiles each)
  gemmP<0, 3, 12, 3, 768, 256><<<256, 512, 131072, stream>>>(
      Xb, Wcat, Qb, Kb, Vt, nullptr, DD, DD, 0, 0, 0);

  // Scores: per batch [2048,768] x [2048,768]^T -> S bf16 ; 256 blocks x 2 tiles
  gemmP<1, 4, 12, 2, 1024, 32><<<256, 512, 131072, stream>>>(
      Qb, Kb, Sb, nullptr, nullptr, nullptr, DD, DD,
      (long)NN * DD, (long)NN * DD, (long)NN * NN);

  softmax_mask<<<BB * NN, 256, 0, stream>>>(Sb, mask);

  // Context: per batch P[2048,2048] x Vt[768,2048]^T -> f32 out ; 256 blocks x 1 tile
  gemmP<2, 3, 32, 1, 0, 32><<<256, 512, 131072, stream>>>(
      Sb, Vt, nullptr, nullptr, nullptr, out, NN, NN,
      (long)NN * NN, (long)DD * NN, (long)NN * DD);
}